// Round 11
// baseline (201.722 us; speedup 1.0000x reference)
//
#include <hip/hip_runtime.h>
#include <math.h>

#define HID   256
#define HEADS 8
#define DH    32
#define BATCH 2
#define SEQ   4096
#define NTOK  (BATCH*SEQ)   // 8192

typedef float f32x4 __attribute__((ext_vector_type(4)));
typedef short s16x8 __attribute__((ext_vector_type(8)));
typedef short s16x4 __attribute__((ext_vector_type(4)));
typedef unsigned int u32x2 __attribute__((ext_vector_type(2)));

__device__ __forceinline__ unsigned short bf16_rne(float f) {
  unsigned u = __float_as_uint(f);
  unsigned r = u + 0x7fffu + ((u >> 16) & 1u);
  return (unsigned short)(r >> 16);
}

__device__ __forceinline__ s16x8 cvt_bf16x8(f32x4 a, f32x4 b) {
  s16x8 t;
  t[0] = (short)bf16_rne(a[0]); t[1] = (short)bf16_rne(a[1]);
  t[2] = (short)bf16_rne(a[2]); t[3] = (short)bf16_rne(a[3]);
  t[4] = (short)bf16_rne(b[0]); t[5] = (short)bf16_rne(b[1]);
  t[6] = (short)bf16_rne(b[2]); t[7] = (short)bf16_rne(b[3]);
  return t;
}

// bank-tiling row permutation for stride-40 LDS tiles (20 banks/row):
// rows ordered 0,4,1,5,2,6,3,7,... so each 8-lane b128 write group
// covers all 32 banks (20*4 = 80 = 16 mod 32).
__device__ __forceinline__ int permrow(int idx) {
  return (idx & ~15) | (idx & 8) | ((idx & 1) << 2) | ((idx >> 1) & 3);
}

// ---------------------------------------------------------------------------
// prep: W -> W^T bf16 (n-major), Wq pre-scaled by 1/(sqrt(32)*ln2) (log2-
// domain scores); mask -> bf16 0/1 array (for the l-MFMA ones operand).
// ---------------------------------------------------------------------------
__global__ __launch_bounds__(256) void prep_kernel(
    const float* __restrict__ Wq, const float* __restrict__ Wk,
    const float* __restrict__ Wv, const float* __restrict__ Wo,
    const int* __restrict__ mask,
    unsigned short* __restrict__ wT,   // 4 mats, layout [w][n][k]
    unsigned short* __restrict__ mbf, float qscale)
{
  int id = blockIdx.x * 256 + threadIdx.x;
  if (id < 4 * 65536) {
    int w = id >> 16;
    int r = id & 65535;
    int n = r >> 8, k = r & 255;
    const float* W = (w == 0) ? Wq : (w == 1) ? Wk : (w == 2) ? Wv : Wo;
    float v = W[k * 256 + n];
    if (w == 0) v *= qscale;
    wT[id] = bf16_rne(v);
  } else if (id < 4 * 65536 + NTOK) {
    int i = id - 4 * 65536;
    mbf[i] = mask[i] ? (unsigned short)0x3F80 : (unsigned short)0;
  }
}

// ---------------------------------------------------------------------------
// qkv_proj: LDS-staged GEMM. z==2 (V) rows of MASKED tokens are zeroed:
// combined with a masked l-ones operand in flash, this equals -inf masking.
//   Q : [token][256]
//   K : [b][h][s][32]           (64B rows)
//   V : [b][h][s/64][d][s%64]   (d-major 4KB subtiles)
// ---------------------------------------------------------------------------
__global__ __launch_bounds__(256) void qkv_proj(
    const float* __restrict__ qin, const float* __restrict__ kin,
    const float* __restrict__ vin, const int* __restrict__ mask,
    const unsigned short* __restrict__ wT,
    const float* __restrict__ bq, const float* __restrict__ bk,
    const float* __restrict__ bv,
    unsigned short* __restrict__ q_ws, unsigned short* __restrict__ kh_ws,
    unsigned short* __restrict__ vt_ws, float qscale)
{
  __shared__ unsigned short As[2][64 * 40];
  __shared__ unsigned short Ws[2][64 * 40];

  const int z = blockIdx.z;
  const float* A = (z == 0) ? qin : (z == 1) ? kin : vin;
  const unsigned short* W = wT + z * 65536;
  const float* bias = (z == 0) ? bq : (z == 1) ? bk : bv;
  const float bscale = (z == 0) ? qscale : 1.f;

  const int tid = threadIdx.x;
  const int lane = tid & 63;
  const int wv = tid >> 6;
  const int l16 = lane & 15, q4 = lane >> 4;
  const int Mblk = blockIdx.x * 64, Nblk = blockIdx.y * 64;
  const int M0 = Mblk + (wv & 1) * 32;
  const int N0 = Nblk + (wv >> 1) * 32;

  const int srow = permrow(tid >> 2), scol = (tid & 3) * 8;
  const float* Aps = A + (size_t)(Mblk + srow) * 256 + scol;
  const unsigned short* Wps = W + (size_t)(Nblk + srow) * 256 + scol;
  unsigned short* adst = &As[0][srow * 40 + scol];
  unsigned short* wdst = &Ws[0][srow * 40 + scol];

  f32x4 areg0, areg1; s16x8 wreg;

#define LOADCH(K) do {                                                         \
    areg0 = *(const f32x4*)(Aps + (K) * 32);                                   \
    areg1 = *(const f32x4*)(Aps + (K) * 32 + 4);                               \
    wreg  = *(const s16x8*)(Wps + (K) * 32);                                   \
  } while (0)
#define WRITECH(B) do {                                                        \
    *(s16x8*)(adst + (B) * (64 * 40)) = cvt_bf16x8(areg0, areg1);              \
    *(s16x8*)(wdst + (B) * (64 * 40)) = wreg;                                  \
  } while (0)

  f32x4 acc[2][2] = {};

  LOADCH(0); WRITECH(0); LOADCH(1);
  for (int k = 0; k < 8; ++k) {
    __syncthreads();
    if (k + 1 < 8) WRITECH((k + 1) & 1);
    if (k + 2 < 8) LOADCH(k + 2);
    const unsigned short* AL = &As[k & 1][0];
    const unsigned short* WL = &Ws[k & 1][0];
    s16x8 af[2], wf[2];
#pragma unroll
    for (int i = 0; i < 2; ++i)
      af[i] = *(const s16x8*)(AL + ((wv & 1) * 32 + i * 16 + l16) * 40 + q4 * 8);
#pragma unroll
    for (int j = 0; j < 2; ++j)
      wf[j] = *(const s16x8*)(WL + ((wv >> 1) * 32 + j * 16 + l16) * 40 + q4 * 8);
#pragma unroll
    for (int i = 0; i < 2; ++i)
#pragma unroll
      for (int j = 0; j < 2; ++j)
        acc[i][j] = __builtin_amdgcn_mfma_f32_16x16x32_bf16(af[i], wf[j], acc[i][j], 0, 0, 0);
  }
#undef LOADCH
#undef WRITECH

#pragma unroll
  for (int j = 0; j < 2; ++j) {
    int n = N0 + j * 16 + l16;
    float bb = bias[n] * bscale;
#pragma unroll
    for (int i = 0; i < 2; ++i) {
      int m0 = M0 + i * 16 + q4 * 4;   // 4 consecutive tokens
      f32x4 c = acc[i][j];
      c[0] += bb; c[1] += bb; c[2] += bb; c[3] += bb;
      if (z == 0) {
#pragma unroll
        for (int r = 0; r < 4; ++r)
          q_ws[(size_t)(m0 + r) * 256 + n] = bf16_rne(c[r]);
      } else if (z == 1) {
        int bi = m0 >> 12, s = m0 & 4095;
        int h = n >> 5, d = n & 31;
        unsigned short* o = kh_ws + ((size_t)(bi * 8 + h) * 4096 + s) * 32 + d;
#pragma unroll
        for (int r = 0; r < 4; ++r) o[(size_t)r * 32] = bf16_rne(c[r]);
      } else {
        // zero masked tokens' V rows (token == flat index m0+r)
#pragma unroll
        for (int r = 0; r < 4; ++r) c[r] *= (float)mask[m0 + r];
        int bi = m0 >> 12, s = m0 & 4095;
        int h = n >> 5, d = n & 31;
        int T = s >> 6, sl = s & 63;
        unsigned lo = (unsigned)bf16_rne(c[0]) | ((unsigned)bf16_rne(c[1]) << 16);
        unsigned hi = (unsigned)bf16_rne(c[2]) | ((unsigned)bf16_rne(c[3]) << 16);
        unsigned* dst = (unsigned*)(vt_ws +
            ((size_t)((bi * 8 + h) * 64 + T) * 32 + d) * 64 + sl);
        dst[0] = lo; dst[1] = hi;
      }
    }
  }
}

// ---------------------------------------------------------------------------
// flash v11 = r9's split-K x4 TLP (2048 blocks, 32 waves/CU -- r10's drop to
// x2 cost 74->89us; occupancy is worth more than partial-write traffic at
// 10-15% HBM) + r10's conflict-free LDS (permuted K rows, V stride 68) +
// truncating P->bf16 (l from the SAME truncated P => ratio-exact).
// ---------------------------------------------------------------------------
__global__ __launch_bounds__(256, 7) void flash_kernel(
    const unsigned short* __restrict__ q_ws, const unsigned short* __restrict__ kh_ws,
    const unsigned short* __restrict__ vt_ws, const unsigned short* __restrict__ mbf,
    float* __restrict__ pO, float* __restrict__ pL)
{
  __shared__ unsigned short Kb[2][64 * 40];   // 10240 B
  __shared__ unsigned short Vb[2][32 * 68];   //  8704 B

  const int idx = blockIdx.x;            // 2048 blocks
  const int qt = idx & 31;
  const int kq = (idx >> 5) & 3;
  const int bh = idx >> 7;
  const int b = bh >> 3, h = bh & 7;
  const int tid = threadIdx.x;
  const int lane = tid & 63;
  const int wv = tid >> 6;
  const int l16 = lane & 15, q4 = lane >> 4;
  const int q0 = qt * 128 + wv * 32;

  s16x8 Qf[2];
#pragma unroll
  for (int qh = 0; qh < 2; ++qh)
    Qf[qh] = *(const s16x8*)(q_ws +
        (size_t)(b * 4096 + q0 + qh * 16 + l16) * 256 + h * 32 + q4 * 8);

  const unsigned short* Ksrc = kh_ws + ((size_t)bh * 4096 + kq * 1024) * 32;
  const unsigned short* Vsrc = vt_ws + (size_t)bh * 64 * 2048 + (size_t)kq * 16 * 2048;
  const unsigned short* Msrc = mbf + b * 4096 + kq * 1024 + q4 * 4;

  // K staging: permuted rows (see permrow comment)
  const int krow = permrow(tid >> 2), kcol = (tid & 3) * 8;
  const unsigned short* kps = Ksrc + krow * 32 + kcol;
  unsigned short* kdst = &Kb[0][krow * 40 + kcol];
  // V staging: row tid>>3 (d), col (tid&7)*8; global source is linear tid*8
  unsigned short* vdst = &Vb[0][(tid >> 3) * 68 + (tid & 7) * 8];

  f32x4 o[2][2] = {{{0.f,0.f,0.f,0.f},{0.f,0.f,0.f,0.f}},
                   {{0.f,0.f,0.f,0.f},{0.f,0.f,0.f,0.f}}};
  f32x4 l[2] = {{0.f,0.f,0.f,0.f},{0.f,0.f,0.f,0.f}};

  const unsigned sel = (l16 == 0) ? 0xFFFFFFFFu : 0u;  // l-operand column select

  s16x8 kreg, vreg;

#define STAGE_LOAD(T) do {                                                     \
    kreg = *(const s16x8*)(kps + (size_t)(T) * 2048);                          \
    vreg = *(const s16x8*)(Vsrc + (size_t)(T) * 2048 + tid * 8);               \
  } while (0)
#define STAGE_WRITE(B) do {                                                    \
    *(s16x8*)(kdst + (B) * (64 * 40)) = kreg;                                  \
    s16x4 _vlo = __builtin_shufflevector(vreg, vreg, 0, 1, 2, 3);              \
    s16x4 _vhi = __builtin_shufflevector(vreg, vreg, 4, 5, 6, 7);              \
    *(s16x4*)(vdst + (B) * (32 * 68)) = _vlo;                                  \
    *(s16x4*)(vdst + (B) * (32 * 68) + 4) = _vhi;                              \
  } while (0)

#define COMPUTE(B, T) do {                                                     \
    const unsigned short* KL = &Kb[B][0];                                      \
    const unsigned short* VL = &Vb[B][0];                                      \
    const f32x4 zz = {0.f, 0.f, 0.f, 0.f};                                     \
    s16x4 mreg[4];                                                             \
    _Pragma("unroll") for (int t = 0; t < 4; ++t)                              \
      mreg[t] = *(const s16x4*)(Msrc + (T) * 64 + t * 16);                     \
    _Pragma("unroll") for (int t = 0; t < 4; ++t) {                            \
      s16x8 kf = *(const s16x8*)(KL + (t * 16 + l16) * 40 + q4 * 8);           \
      f32x4 sc0 = __builtin_amdgcn_mfma_f32_16x16x32_bf16(kf, Qf[0], zz, 0, 0, 0); \
      f32x4 sc1 = __builtin_amdgcn_mfma_f32_16x16x32_bf16(kf, Qf[1], zz, 0, 0, 0); \
      unsigned a0 = __float_as_uint(__builtin_amdgcn_exp2f(sc0[0]));           \
      unsigned a1 = __float_as_uint(__builtin_amdgcn_exp2f(sc0[1]));           \
      unsigned a2 = __float_as_uint(__builtin_amdgcn_exp2f(sc0[2]));           \
      unsigned a3 = __float_as_uint(__builtin_amdgcn_exp2f(sc0[3]));           \
      unsigned c0 = __float_as_uint(__builtin_amdgcn_exp2f(sc1[0]));           \
      unsigned c1 = __float_as_uint(__builtin_amdgcn_exp2f(sc1[1]));           \
      unsigned c2 = __float_as_uint(__builtin_amdgcn_exp2f(sc1[2]));           \
      unsigned c3 = __float_as_uint(__builtin_amdgcn_exp2f(sc1[3]));           \
      u32x2 pk0, pk1;                                                          \
      pk0[0] = __builtin_amdgcn_perm(a1, a0, 0x07060302u);                     \
      pk0[1] = __builtin_amdgcn_perm(a3, a2, 0x07060302u);                     \
      pk1[0] = __builtin_amdgcn_perm(c1, c0, 0x07060302u);                     \
      pk1[1] = __builtin_amdgcn_perm(c3, c2, 0x07060302u);                     \
      s16x4 pf0 = __builtin_bit_cast(s16x4, pk0);                              \
      s16x4 pf1 = __builtin_bit_cast(s16x4, pk1);                              \
      u32x2 mm = __builtin_bit_cast(u32x2, mreg[t]);                           \
      mm[0] &= sel; mm[1] &= sel;                                              \
      s16x4 onesb = __builtin_bit_cast(s16x4, mm);                             \
      s16x4 vf0 = *(const s16x4*)(VL + l16 * 68 + t * 16 + q4 * 4);            \
      s16x4 vf1 = *(const s16x4*)(VL + (l16 + 16) * 68 + t * 16 + q4 * 4);     \
      o[0][0] = __builtin_amdgcn_mfma_f32_16x16x16bf16_1k(pf0, vf0, o[0][0], 0, 0, 0); \
      o[0][1] = __builtin_amdgcn_mfma_f32_16x16x16bf16_1k(pf0, vf1, o[0][1], 0, 0, 0); \
      o[1][0] = __builtin_amdgcn_mfma_f32_16x16x16bf16_1k(pf1, vf0, o[1][0], 0, 0, 0); \
      o[1][1] = __builtin_amdgcn_mfma_f32_16x16x16bf16_1k(pf1, vf1, o[1][1], 0, 0, 0); \
      l[0] = __builtin_amdgcn_mfma_f32_16x16x16bf16_1k(pf0, onesb, l[0], 0, 0, 0); \
      l[1] = __builtin_amdgcn_mfma_f32_16x16x16bf16_1k(pf1, onesb, l[1], 0, 0, 0); \
    }                                                                          \
  } while (0)

  STAGE_LOAD(0); STAGE_WRITE(0);
  STAGE_LOAD(1);

  for (int T = 0; T < 16; ++T) {
    __syncthreads();                       // fences buf[(T+1)&1] reuse
    if (T + 1 < 16) STAGE_WRITE((T + 1) & 1);   // from loads issued iter T-1
    if (T + 2 < 16) STAGE_LOAD(T + 2);          // in flight across COMPUTE
    COMPUTE(T & 1, T);
  }
#undef STAGE_LOAD
#undef STAGE_WRITE
#undef COMPUTE

  // f32 partials: pO[kq][bh][q][d], pL[kq][bh][q]
  float* pob = pO + (((size_t)kq * 16 + bh) * 4096 + q0) * 32;
#pragma unroll
  for (int qh = 0; qh < 2; ++qh)
#pragma unroll
    for (int r = 0; r < 4; ++r) {
      int q = qh * 16 + q4 * 4 + r;
      pob[(size_t)q * 32 + l16]      = o[qh][0][r];
      pob[(size_t)q * 32 + l16 + 16] = o[qh][1][r];
    }
  if (l16 == 0) {
    float* plb = pL + ((size_t)kq * 16 + bh) * 4096 + q0;
#pragma unroll
    for (int qh = 0; qh < 2; ++qh)
#pragma unroll
      for (int r = 0; r < 4; ++r)
        plb[qh * 16 + q4 * 4 + r] = l[qh][r];
  }
}

// ---------------------------------------------------------------------------
// combine: wtd = (sum of 4 O partials) / (sum of 4 l partials), bf16.
// ---------------------------------------------------------------------------
__global__ __launch_bounds__(256) void combine_kernel(
    const float* __restrict__ pO, const float* __restrict__ pL,
    unsigned short* __restrict__ wtd)
{
  int id = blockIdx.x * 256 + threadIdx.x;   // 524288 = 16bh * 4096q * 8
  int d4 = id & 7;
  int q  = (id >> 3) & 4095;
  int bh = id >> 15;
  int b = bh >> 3, h = bh & 7;
  const size_t OS = (size_t)16 * 4096 * 32;
  const size_t LS = (size_t)16 * 4096;
  size_t i0 = ((size_t)bh * 4096 + q) * 32 + d4 * 4;
  f32x4 s = *(const f32x4*)(pO + i0);
  float lt = pL[(size_t)bh * 4096 + q];
#pragma unroll
  for (int kq = 1; kq < 4; ++kq) {
    f32x4 c = *(const f32x4*)(pO + kq * OS + i0);
    s[0] += c[0]; s[1] += c[1]; s[2] += c[2]; s[3] += c[3];
    lt += pL[kq * LS + (size_t)bh * 4096 + q];
  }
  float inv = 1.0f / lt;
  unsigned lo = (unsigned)bf16_rne(s[0] * inv) | ((unsigned)bf16_rne(s[1] * inv) << 16);
  unsigned hi = (unsigned)bf16_rne(s[2] * inv) | ((unsigned)bf16_rne(s[3] * inv) << 16);
  unsigned* dst = (unsigned*)(wtd + ((size_t)(b * 4096 + q) * 256) + h * 32 + d4 * 4);
  dst[0] = lo; dst[1] = hi;
}

// ---------------------------------------------------------------------------
// o_proj: out = wtd(bf16) @ Wo + bo, fp32 out.
// ---------------------------------------------------------------------------
__global__ __launch_bounds__(256) void o_proj(
    const unsigned short* __restrict__ wtd, const unsigned short* __restrict__ woT,
    const float* __restrict__ bo, float* __restrict__ out)
{
  const int lane = threadIdx.x & 63;
  const int wv = threadIdx.x >> 6;
  const int l16 = lane & 15, q4 = lane >> 4;
  const int M0 = blockIdx.x * 64 + (wv & 1) * 32;
  const int N0 = blockIdx.y * 64 + (wv >> 1) * 32;

  f32x4 acc[2][2] = {};
  for (int k0 = 0; k0 < 256; k0 += 32) {
    s16x8 af[2], wf[2];
#pragma unroll
    for (int i = 0; i < 2; ++i)
      af[i] = *(const s16x8*)(wtd + (size_t)(M0 + i * 16 + l16) * 256 + k0 + q4 * 8);
#pragma unroll
    for (int j = 0; j < 2; ++j)
      wf[j] = *(const s16x8*)(woT + (size_t)(N0 + j * 16 + l16) * 256 + k0 + q4 * 8);
#pragma unroll
    for (int i = 0; i < 2; ++i)
#pragma unroll
      for (int j = 0; j < 2; ++j)
        acc[i][j] = __builtin_amdgcn_mfma_f32_16x16x32_bf16(af[i], wf[j], acc[i][j], 0, 0, 0);
  }

#pragma unroll
  for (int j = 0; j < 2; ++j) {
    int n = N0 + j * 16 + l16;
    float bb = bo[n];
#pragma unroll
    for (int i = 0; i < 2; ++i) {
      int m0 = M0 + i * 16 + q4 * 4;
#pragma unroll
      for (int r = 0; r < 4; ++r)
        out[(size_t)(m0 + r) * 256 + n] = acc[i][j][r] + bb;
    }
  }
}

// ---------------------------------------------------------------------------
extern "C" void kernel_launch(void* const* d_in, const int* in_sizes, int n_in,
                              void* d_out, int out_size, void* d_ws, size_t ws_size,
                              hipStream_t stream) {
  const float* query = (const float*)d_in[0];
  const float* key   = (const float*)d_in[1];
  const float* value = (const float*)d_in[2];
  const int*   mask  = (const int*)d_in[3];
  const float* Wq = (const float*)d_in[4];
  const float* bq = (const float*)d_in[5];
  const float* Wk = (const float*)d_in[6];
  const float* bk = (const float*)d_in[7];
  const float* Wv = (const float*)d_in[8];
  const float* bv = (const float*)d_in[9];
  const float* Wo = (const float*)d_in[10];
  const float* bo = (const float*)d_in[11];
  float* out = (float*)d_out;

  char* p = (char*)d_ws;
  unsigned short* q_ws  = (unsigned short*)p; p += (size_t)NTOK * HID * 2;
  unsigned short* kh_ws = (unsigned short*)p; p += (size_t)NTOK * HID * 2;
  unsigned short* vt_ws = (unsigned short*)p; p += (size_t)NTOK * HID * 2;
  unsigned short* wtd   = (unsigned short*)p; p += (size_t)NTOK * HID * 2;
  unsigned short* wT    = (unsigned short*)p; p += (size_t)4 * 65536 * 2;
  unsigned short* mbf   = (unsigned short*)p; p += (size_t)NTOK * 2;
  float* pO             = (float*)p;          p += (size_t)4 * 16 * 4096 * 32 * 4;
  float* pL             = (float*)p;          p += (size_t)4 * 16 * 4096 * 4;

  const float qscale = 1.0f / (sqrtf(32.0f) * logf(2.0f)); // softmax scale + log2 domain

  prep_kernel<<<(4 * 65536 + NTOK + 255) / 256, 256, 0, stream>>>(
      Wq, Wk, Wv, Wo, mask, wT, mbf, qscale);
  qkv_proj<<<dim3(NTOK / 64, HID / 64, 3), 256, 0, stream>>>(
      query, key, value, mask, wT, bq, bk, bv, q_ws, kh_ws, vt_ws, qscale);
  flash_kernel<<<dim3(2048), 256, 0, stream>>>(
      q_ws, kh_ws, vt_ws, mbf, pO, pL);
  combine_kernel<<<dim3(2048), 256, 0, stream>>>(pO, pL, wtd);
  o_proj<<<dim3(NTOK / 64, HID / 64), 256, 0, stream>>>(
      wtd, wT + 3 * 65536, bo, out);
}

// Round 12
// 180.044 us; speedup vs baseline: 1.1204x; 1.1204x over previous
//
#include <hip/hip_runtime.h>
#include <math.h>

#define HID   256
#define HEADS 8
#define DH    32
#define BATCH 2
#define SEQ   4096
#define NTOK  (BATCH*SEQ)   // 8192

typedef float f32x4 __attribute__((ext_vector_type(4)));
typedef short s16x8 __attribute__((ext_vector_type(8)));
typedef short s16x4 __attribute__((ext_vector_type(4)));
typedef unsigned int u32x2 __attribute__((ext_vector_type(2)));

__device__ __forceinline__ unsigned short bf16_rne(float f) {
  unsigned u = __float_as_uint(f);
  unsigned r = u + 0x7fffu + ((u >> 16) & 1u);
  return (unsigned short)(r >> 16);
}

__device__ __forceinline__ float bf16_to_f32(unsigned short h) {
  return __uint_as_float(((unsigned)h) << 16);
}

__device__ __forceinline__ s16x8 cvt_bf16x8(f32x4 a, f32x4 b) {
  s16x8 t;
  t[0] = (short)bf16_rne(a[0]); t[1] = (short)bf16_rne(a[1]);
  t[2] = (short)bf16_rne(a[2]); t[3] = (short)bf16_rne(a[3]);
  t[4] = (short)bf16_rne(b[0]); t[5] = (short)bf16_rne(b[1]);
  t[6] = (short)bf16_rne(b[2]); t[7] = (short)bf16_rne(b[3]);
  return t;
}

// ---------------------------------------------------------------------------
// prep: W -> W^T bf16 (n-major), Wq pre-scaled by 1/(sqrt(32)*ln2) (log2-
// domain scores); mask -> bf16 0/1 array (for the l-MFMA ones operand).
// ---------------------------------------------------------------------------
__global__ __launch_bounds__(256) void prep_kernel(
    const float* __restrict__ Wq, const float* __restrict__ Wk,
    const float* __restrict__ Wv, const float* __restrict__ Wo,
    const int* __restrict__ mask,
    unsigned short* __restrict__ wT,   // 4 mats, layout [w][n][k]
    unsigned short* __restrict__ mbf, float qscale)
{
  int id = blockIdx.x * 256 + threadIdx.x;
  if (id < 4 * 65536) {
    int w = id >> 16;
    int r = id & 65535;
    int n = r >> 8, k = r & 255;
    const float* W = (w == 0) ? Wq : (w == 1) ? Wk : (w == 2) ? Wv : Wo;
    float v = W[k * 256 + n];
    if (w == 0) v *= qscale;
    wT[id] = bf16_rne(v);
  } else if (id < 4 * 65536 + NTOK) {
    int i = id - 4 * 65536;
    mbf[i] = mask[i] ? (unsigned short)0x3F80 : (unsigned short)0;
  }
}

// ---------------------------------------------------------------------------
// qkv_proj: LDS-staged GEMM (r9 layout: LINEAR staging rows -- the r10/r11
// permuted variant regressed end-to-end despite lower counted conflicts).
// z==2 (V) rows of MASKED tokens are zeroed: with the masked l-ones operand
// in flash this equals -inf masking.
//   Q : [token][256]
//   K : [b][h][s][32]           (64B rows)
//   V : [b][h][s/64][d][s%64]   (d-major 4KB subtiles)
// ---------------------------------------------------------------------------
__global__ __launch_bounds__(256) void qkv_proj(
    const float* __restrict__ qin, const float* __restrict__ kin,
    const float* __restrict__ vin, const int* __restrict__ mask,
    const unsigned short* __restrict__ wT,
    const float* __restrict__ bq, const float* __restrict__ bk,
    const float* __restrict__ bv,
    unsigned short* __restrict__ q_ws, unsigned short* __restrict__ kh_ws,
    unsigned short* __restrict__ vt_ws, float qscale)
{
  __shared__ unsigned short As[2][64 * 40];
  __shared__ unsigned short Ws[2][64 * 40];

  const int z = blockIdx.z;
  const float* A = (z == 0) ? qin : (z == 1) ? kin : vin;
  const unsigned short* W = wT + z * 65536;
  const float* bias = (z == 0) ? bq : (z == 1) ? bk : bv;
  const float bscale = (z == 0) ? qscale : 1.f;

  const int tid = threadIdx.x;
  const int lane = tid & 63;
  const int wv = tid >> 6;
  const int l16 = lane & 15, q4 = lane >> 4;
  const int Mblk = blockIdx.x * 64, Nblk = blockIdx.y * 64;
  const int M0 = Mblk + (wv & 1) * 32;
  const int N0 = Nblk + (wv >> 1) * 32;

  const int srow = tid >> 2, scol = (tid & 3) * 8;
  const float* Aps = A + (size_t)(Mblk + srow) * 256 + scol;
  const unsigned short* Wps = W + (size_t)(Nblk + srow) * 256 + scol;
  unsigned short* adst = &As[0][srow * 40 + scol];
  unsigned short* wdst = &Ws[0][srow * 40 + scol];

  f32x4 areg0, areg1; s16x8 wreg;

#define LOADCH(K) do {                                                         \
    areg0 = *(const f32x4*)(Aps + (K) * 32);                                   \
    areg1 = *(const f32x4*)(Aps + (K) * 32 + 4);                               \
    wreg  = *(const s16x8*)(Wps + (K) * 32);                                   \
  } while (0)
#define WRITECH(B) do {                                                        \
    *(s16x8*)(adst + (B) * (64 * 40)) = cvt_bf16x8(areg0, areg1);              \
    *(s16x8*)(wdst + (B) * (64 * 40)) = wreg;                                  \
  } while (0)

  f32x4 acc[2][2] = {};

  LOADCH(0); WRITECH(0); LOADCH(1);
  for (int k = 0; k < 8; ++k) {
    __syncthreads();
    if (k + 1 < 8) WRITECH((k + 1) & 1);
    if (k + 2 < 8) LOADCH(k + 2);
    const unsigned short* AL = &As[k & 1][0];
    const unsigned short* WL = &Ws[k & 1][0];
    s16x8 af[2], wf[2];
#pragma unroll
    for (int i = 0; i < 2; ++i)
      af[i] = *(const s16x8*)(AL + ((wv & 1) * 32 + i * 16 + l16) * 40 + q4 * 8);
#pragma unroll
    for (int j = 0; j < 2; ++j)
      wf[j] = *(const s16x8*)(WL + ((wv >> 1) * 32 + j * 16 + l16) * 40 + q4 * 8);
#pragma unroll
    for (int i = 0; i < 2; ++i)
#pragma unroll
      for (int j = 0; j < 2; ++j)
        acc[i][j] = __builtin_amdgcn_mfma_f32_16x16x32_bf16(af[i], wf[j], acc[i][j], 0, 0, 0);
  }
#undef LOADCH
#undef WRITECH

#pragma unroll
  for (int j = 0; j < 2; ++j) {
    int n = N0 + j * 16 + l16;
    float bb = bias[n] * bscale;
#pragma unroll
    for (int i = 0; i < 2; ++i) {
      int m0 = M0 + i * 16 + q4 * 4;   // 4 consecutive tokens
      f32x4 c = acc[i][j];
      c[0] += bb; c[1] += bb; c[2] += bb; c[3] += bb;
      if (z == 0) {
#pragma unroll
        for (int r = 0; r < 4; ++r)
          q_ws[(size_t)(m0 + r) * 256 + n] = bf16_rne(c[r]);
      } else if (z == 1) {
        int bi = m0 >> 12, s = m0 & 4095;
        int h = n >> 5, d = n & 31;
        unsigned short* o = kh_ws + ((size_t)(bi * 8 + h) * 4096 + s) * 32 + d;
#pragma unroll
        for (int r = 0; r < 4; ++r) o[(size_t)r * 32] = bf16_rne(c[r]);
      } else {
        // zero masked tokens' V rows (token == flat index m0+r)
#pragma unroll
        for (int r = 0; r < 4; ++r) c[r] *= (float)mask[m0 + r];
        int bi = m0 >> 12, s = m0 & 4095;
        int h = n >> 5, d = n & 31;
        int T = s >> 6, sl = s & 63;
        unsigned lo = (unsigned)bf16_rne(c[0]) | ((unsigned)bf16_rne(c[1]) << 16);
        unsigned hi = (unsigned)bf16_rne(c[2]) | ((unsigned)bf16_rne(c[3]) << 16);
        unsigned* dst = (unsigned*)(vt_ws +
            ((size_t)((bi * 8 + h) * 64 + T) * 32 + d) * 64 + sl);
        dst[0] = lo; dst[1] = hi;
      }
    }
  }
}

// ---------------------------------------------------------------------------
// flash v12 = EXACT r9 kernel (74us measured: split-K x4, ring-2 LDS,
// linear K staging stride 40, V stride 72 single-b128 staging, +0x8000
// rounding). The r10/r11 "conflict-free" relayout regressed 74->88us at
// identical grid/occupancy -- measured layout wins over modeled layout.
// ONE change vs r9: partial O written as bf16 (halves pO traffic; l stays
// f32; adds ~2e-4 abs error, well within threshold).
// ---------------------------------------------------------------------------
__global__ __launch_bounds__(256, 7) void flash_kernel(
    const unsigned short* __restrict__ q_ws, const unsigned short* __restrict__ kh_ws,
    const unsigned short* __restrict__ vt_ws, const unsigned short* __restrict__ mbf,
    unsigned short* __restrict__ pO, float* __restrict__ pL)
{
  __shared__ unsigned short Kb[2][64 * 40];   // 10240 B
  __shared__ unsigned short Vb[2][32 * 72];   //  9216 B

  const int idx = blockIdx.x;            // 2048 blocks
  const int qt = idx & 31;
  const int kq = (idx >> 5) & 3;
  const int bh = idx >> 7;
  const int b = bh >> 3, h = bh & 7;
  const int tid = threadIdx.x;
  const int lane = tid & 63;
  const int wv = tid >> 6;
  const int l16 = lane & 15, q4 = lane >> 4;
  const int q0 = qt * 128 + wv * 32;

  s16x8 Qf[2];
#pragma unroll
  for (int qh = 0; qh < 2; ++qh)
    Qf[qh] = *(const s16x8*)(q_ws +
        (size_t)(b * 4096 + q0 + qh * 16 + l16) * 256 + h * 32 + q4 * 8);

  const unsigned short* Ksrc = kh_ws + ((size_t)bh * 4096 + kq * 1024) * 32;
  const unsigned short* Vsrc = vt_ws + (size_t)bh * 64 * 2048 + (size_t)kq * 16 * 2048;
  const unsigned short* Msrc = mbf + b * 4096 + kq * 1024 + q4 * 4;

  unsigned short* kdst = &Kb[0][(tid >> 2) * 40 + (tid & 3) * 8];
  unsigned short* vdst = &Vb[0][(tid >> 3) * 72 + (tid & 7) * 8];

  f32x4 o[2][2] = {{{0.f,0.f,0.f,0.f},{0.f,0.f,0.f,0.f}},
                   {{0.f,0.f,0.f,0.f},{0.f,0.f,0.f,0.f}}};
  f32x4 l[2] = {{0.f,0.f,0.f,0.f},{0.f,0.f,0.f,0.f}};

  const unsigned sel = (l16 == 0) ? 0xFFFFFFFFu : 0u;  // l-operand column select

  s16x8 kreg, vreg;

#define STAGE_LOAD(T) do {                                                     \
    kreg = *(const s16x8*)(Ksrc + (size_t)(T) * 2048 + tid * 8);               \
    vreg = *(const s16x8*)(Vsrc + (size_t)(T) * 2048 + tid * 8);               \
  } while (0)
#define STAGE_WRITE(B) do {                                                    \
    *(s16x8*)(kdst + (B) * (64 * 40)) = kreg;                                  \
    *(s16x8*)(vdst + (B) * (32 * 72)) = vreg;                                  \
  } while (0)

#define COMPUTE(B, T) do {                                                     \
    const unsigned short* KL = &Kb[B][0];                                      \
    const unsigned short* VL = &Vb[B][0];                                      \
    const f32x4 zz = {0.f, 0.f, 0.f, 0.f};                                     \
    s16x4 mreg[4];                                                             \
    _Pragma("unroll") for (int t = 0; t < 4; ++t)                              \
      mreg[t] = *(const s16x4*)(Msrc + (T) * 64 + t * 16);                     \
    _Pragma("unroll") for (int t = 0; t < 4; ++t) {                            \
      s16x8 kf = *(const s16x8*)(KL + (t * 16 + l16) * 40 + q4 * 8);           \
      f32x4 sc0 = __builtin_amdgcn_mfma_f32_16x16x32_bf16(kf, Qf[0], zz, 0, 0, 0); \
      f32x4 sc1 = __builtin_amdgcn_mfma_f32_16x16x32_bf16(kf, Qf[1], zz, 0, 0, 0); \
      unsigned a0 = __float_as_uint(__builtin_amdgcn_exp2f(sc0[0])) + 0x8000u; \
      unsigned a1 = __float_as_uint(__builtin_amdgcn_exp2f(sc0[1])) + 0x8000u; \
      unsigned a2 = __float_as_uint(__builtin_amdgcn_exp2f(sc0[2])) + 0x8000u; \
      unsigned a3 = __float_as_uint(__builtin_amdgcn_exp2f(sc0[3])) + 0x8000u; \
      unsigned c0 = __float_as_uint(__builtin_amdgcn_exp2f(sc1[0])) + 0x8000u; \
      unsigned c1 = __float_as_uint(__builtin_amdgcn_exp2f(sc1[1])) + 0x8000u; \
      unsigned c2 = __float_as_uint(__builtin_amdgcn_exp2f(sc1[2])) + 0x8000u; \
      unsigned c3 = __float_as_uint(__builtin_amdgcn_exp2f(sc1[3])) + 0x8000u; \
      u32x2 pk0, pk1;                                                          \
      pk0[0] = __builtin_amdgcn_perm(a1, a0, 0x07060302u);                     \
      pk0[1] = __builtin_amdgcn_perm(a3, a2, 0x07060302u);                     \
      pk1[0] = __builtin_amdgcn_perm(c1, c0, 0x07060302u);                     \
      pk1[1] = __builtin_amdgcn_perm(c3, c2, 0x07060302u);                     \
      s16x4 pf0 = __builtin_bit_cast(s16x4, pk0);                              \
      s16x4 pf1 = __builtin_bit_cast(s16x4, pk1);                              \
      u32x2 mm = __builtin_bit_cast(u32x2, mreg[t]);                           \
      mm[0] &= sel; mm[1] &= sel;                                              \
      s16x4 onesb = __builtin_bit_cast(s16x4, mm);                             \
      s16x4 vf0 = *(const s16x4*)(VL + l16 * 72 + t * 16 + q4 * 4);            \
      s16x4 vf1 = *(const s16x4*)(VL + (l16 + 16) * 72 + t * 16 + q4 * 4);     \
      o[0][0] = __builtin_amdgcn_mfma_f32_16x16x16bf16_1k(pf0, vf0, o[0][0], 0, 0, 0); \
      o[0][1] = __builtin_amdgcn_mfma_f32_16x16x16bf16_1k(pf0, vf1, o[0][1], 0, 0, 0); \
      o[1][0] = __builtin_amdgcn_mfma_f32_16x16x16bf16_1k(pf1, vf0, o[1][0], 0, 0, 0); \
      o[1][1] = __builtin_amdgcn_mfma_f32_16x16x16bf16_1k(pf1, vf1, o[1][1], 0, 0, 0); \
      l[0] = __builtin_amdgcn_mfma_f32_16x16x16bf16_1k(pf0, onesb, l[0], 0, 0, 0); \
      l[1] = __builtin_amdgcn_mfma_f32_16x16x16bf16_1k(pf1, onesb, l[1], 0, 0, 0); \
    }                                                                          \
  } while (0)

  STAGE_LOAD(0); STAGE_WRITE(0);
  STAGE_LOAD(1);

  for (int T = 0; T < 16; ++T) {
    __syncthreads();                       // fences buf[(T+1)&1] reuse
    if (T + 1 < 16) STAGE_WRITE((T + 1) & 1);   // from loads issued iter T-1
    if (T + 2 < 16) STAGE_LOAD(T + 2);          // in flight across COMPUTE
    COMPUTE(T & 1, T);
  }
#undef STAGE_LOAD
#undef STAGE_WRITE
#undef COMPUTE

  // bf16 partials: pO[kq][bh][q][d]; l (f32): pL[kq][bh][q]
  unsigned short* pob = pO + (((size_t)kq * 16 + bh) * 4096 + q0) * 32;
#pragma unroll
  for (int qh = 0; qh < 2; ++qh)
#pragma unroll
    for (int r = 0; r < 4; ++r) {
      int q = qh * 16 + q4 * 4 + r;
      pob[(size_t)q * 32 + l16]      = bf16_rne(o[qh][0][r]);
      pob[(size_t)q * 32 + l16 + 16] = bf16_rne(o[qh][1][r]);
    }
  if (l16 == 0) {
    float* plb = pL + ((size_t)kq * 16 + bh) * 4096 + q0;
#pragma unroll
    for (int qh = 0; qh < 2; ++qh)
#pragma unroll
      for (int r = 0; r < 4; ++r)
        plb[qh * 16 + q4 * 4 + r] = l[qh][r];
  }
}

// ---------------------------------------------------------------------------
// combine: wtd = (sum of 4 bf16 O partials) / (sum of 4 f32 l partials).
// 8 d per thread: 16B loads/stores throughout.
// ---------------------------------------------------------------------------
__global__ __launch_bounds__(256) void combine_kernel(
    const unsigned short* __restrict__ pO, const float* __restrict__ pL,
    unsigned short* __restrict__ wtd)
{
  int id = blockIdx.x * 256 + threadIdx.x;   // 262144 = 16bh * 4096q * 4
  int d8 = id & 3;
  int q  = (id >> 2) & 4095;
  int bh = id >> 14;
  int b = bh >> 3, h = bh & 7;
  const size_t OS = (size_t)16 * 4096 * 32;  // ushort elements per kq slab
  const size_t LS = (size_t)16 * 4096;
  size_t i0 = ((size_t)bh * 4096 + q) * 32 + d8 * 8;

  float s[8] = {0.f,0.f,0.f,0.f,0.f,0.f,0.f,0.f};
  float lt = 0.f;
#pragma unroll
  for (int kq = 0; kq < 4; ++kq) {
    s16x8 v = *(const s16x8*)(pO + kq * OS + i0);
#pragma unroll
    for (int j = 0; j < 8; ++j) s[j] += bf16_to_f32((unsigned short)v[j]);
    lt += pL[kq * LS + (size_t)bh * 4096 + q];
  }
  float inv = 1.0f / lt;
  s16x8 outp;
#pragma unroll
  for (int j = 0; j < 8; ++j) outp[j] = (short)bf16_rne(s[j] * inv);
  *(s16x8*)(wtd + ((size_t)(b * 4096 + q) * 256) + h * 32 + d8 * 8) = outp;
}

// ---------------------------------------------------------------------------
// o_proj: out = wtd(bf16) @ Wo + bo, fp32 out.
// ---------------------------------------------------------------------------
__global__ __launch_bounds__(256) void o_proj(
    const unsigned short* __restrict__ wtd, const unsigned short* __restrict__ woT,
    const float* __restrict__ bo, float* __restrict__ out)
{
  const int lane = threadIdx.x & 63;
  const int wv = threadIdx.x >> 6;
  const int l16 = lane & 15, q4 = lane >> 4;
  const int M0 = blockIdx.x * 64 + (wv & 1) * 32;
  const int N0 = blockIdx.y * 64 + (wv >> 1) * 32;

  f32x4 acc[2][2] = {};
  for (int k0 = 0; k0 < 256; k0 += 32) {
    s16x8 af[2], wf[2];
#pragma unroll
    for (int i = 0; i < 2; ++i)
      af[i] = *(const s16x8*)(wtd + (size_t)(M0 + i * 16 + l16) * 256 + k0 + q4 * 8);
#pragma unroll
    for (int j = 0; j < 2; ++j)
      wf[j] = *(const s16x8*)(woT + (size_t)(N0 + j * 16 + l16) * 256 + k0 + q4 * 8);
#pragma unroll
    for (int i = 0; i < 2; ++i)
#pragma unroll
      for (int j = 0; j < 2; ++j)
        acc[i][j] = __builtin_amdgcn_mfma_f32_16x16x32_bf16(af[i], wf[j], acc[i][j], 0, 0, 0);
  }

#pragma unroll
  for (int j = 0; j < 2; ++j) {
    int n = N0 + j * 16 + l16;
    float bb = bo[n];
#pragma unroll
    for (int i = 0; i < 2; ++i) {
      int m0 = M0 + i * 16 + q4 * 4;
#pragma unroll
      for (int r = 0; r < 4; ++r)
        out[(size_t)(m0 + r) * 256 + n] = acc[i][j][r] + bb;
    }
  }
}

// ---------------------------------------------------------------------------
extern "C" void kernel_launch(void* const* d_in, const int* in_sizes, int n_in,
                              void* d_out, int out_size, void* d_ws, size_t ws_size,
                              hipStream_t stream) {
  const float* query = (const float*)d_in[0];
  const float* key   = (const float*)d_in[1];
  const float* value = (const float*)d_in[2];
  const int*   mask  = (const int*)d_in[3];
  const float* Wq = (const float*)d_in[4];
  const float* bq = (const float*)d_in[5];
  const float* Wk = (const float*)d_in[6];
  const float* bk = (const float*)d_in[7];
  const float* Wv = (const float*)d_in[8];
  const float* bv = (const float*)d_in[9];
  const float* Wo = (const float*)d_in[10];
  const float* bo = (const float*)d_in[11];
  float* out = (float*)d_out;

  char* p = (char*)d_ws;
  unsigned short* q_ws  = (unsigned short*)p; p += (size_t)NTOK * HID * 2;
  unsigned short* kh_ws = (unsigned short*)p; p += (size_t)NTOK * HID * 2;
  unsigned short* vt_ws = (unsigned short*)p; p += (size_t)NTOK * HID * 2;
  unsigned short* wtd   = (unsigned short*)p; p += (size_t)NTOK * HID * 2;
  unsigned short* wT    = (unsigned short*)p; p += (size_t)4 * 65536 * 2;
  unsigned short* mbf   = (unsigned short*)p; p += (size_t)NTOK * 2;
  unsigned short* pO    = (unsigned short*)p; p += (size_t)4 * 16 * 4096 * 32 * 2;
  float* pL             = (float*)p;          p += (size_t)4 * 16 * 4096 * 4;

  const float qscale = 1.0f / (sqrtf(32.0f) * logf(2.0f)); // softmax scale + log2 domain

  prep_kernel<<<(4 * 65536 + NTOK + 255) / 256, 256, 0, stream>>>(
      Wq, Wk, Wv, Wo, mask, wT, mbf, qscale);
  qkv_proj<<<dim3(NTOK / 64, HID / 64, 3), 256, 0, stream>>>(
      query, key, value, mask, wT, bq, bk, bv, q_ws, kh_ws, vt_ws, qscale);
  flash_kernel<<<dim3(2048), 256, 0, stream>>>(
      q_ws, kh_ws, vt_ws, mbf, pO, pL);
  combine_kernel<<<dim3(1024), 256, 0, stream>>>(pO, pL, wtd);
  o_proj<<<dim3(NTOK / 64, HID / 64), 256, 0, stream>>>(
      wtd, wT + 3 * 65536, bo, out);
}

// Round 13
// 174.435 us; speedup vs baseline: 1.1564x; 1.0322x over previous
//
#include <hip/hip_runtime.h>
#include <math.h>

#define HID   256
#define HEADS 8
#define DH    32
#define BATCH 2
#define SEQ   4096
#define NTOK  (BATCH*SEQ)   // 8192

typedef float f32x4 __attribute__((ext_vector_type(4)));
typedef short s16x8 __attribute__((ext_vector_type(8)));
typedef short s16x4 __attribute__((ext_vector_type(4)));
typedef unsigned int u32x2 __attribute__((ext_vector_type(2)));

__device__ __forceinline__ unsigned short bf16_rne(float f) {
  unsigned u = __float_as_uint(f);
  unsigned r = u + 0x7fffu + ((u >> 16) & 1u);
  return (unsigned short)(r >> 16);
}

__device__ __forceinline__ float bf16_to_f32(unsigned short h) {
  return __uint_as_float(((unsigned)h) << 16);
}

__device__ __forceinline__ s16x8 cvt_bf16x8(f32x4 a, f32x4 b) {
  s16x8 t;
  t[0] = (short)bf16_rne(a[0]); t[1] = (short)bf16_rne(a[1]);
  t[2] = (short)bf16_rne(a[2]); t[3] = (short)bf16_rne(a[3]);
  t[4] = (short)bf16_rne(b[0]); t[5] = (short)bf16_rne(b[1]);
  t[6] = (short)bf16_rne(b[2]); t[7] = (short)bf16_rne(b[3]);
  return t;
}

// ---------------------------------------------------------------------------
// prep: W -> W^T bf16 (n-major), Wq pre-scaled by 1/(sqrt(32)*ln2) (log2-
// domain scores); mask -> bf16 0/1 array (for the l-MFMA ones operand).
// ---------------------------------------------------------------------------
__global__ __launch_bounds__(256) void prep_kernel(
    const float* __restrict__ Wq, const float* __restrict__ Wk,
    const float* __restrict__ Wv, const float* __restrict__ Wo,
    const int* __restrict__ mask,
    unsigned short* __restrict__ wT,   // 4 mats, layout [w][n][k]
    unsigned short* __restrict__ mbf, float qscale)
{
  int id = blockIdx.x * 256 + threadIdx.x;
  if (id < 4 * 65536) {
    int w = id >> 16;
    int r = id & 65535;
    int n = r >> 8, k = r & 255;
    const float* W = (w == 0) ? Wq : (w == 1) ? Wk : (w == 2) ? Wv : Wo;
    float v = W[k * 256 + n];
    if (w == 0) v *= qscale;
    wT[id] = bf16_rne(v);
  } else if (id < 4 * 65536 + NTOK) {
    int i = id - 4 * 65536;
    mbf[i] = mask[i] ? (unsigned short)0x3F80 : (unsigned short)0;
  }
}

// ---------------------------------------------------------------------------
// qkv_proj: LDS-staged GEMM (r9/r12 layout, byte-identical).
//   Q : [token][256]
//   K : [b][h][s][32]           (64B rows)
//   V : [b][h][s/64][d][s%64]   (d-major 4KB subtiles)
// ---------------------------------------------------------------------------
__global__ __launch_bounds__(256) void qkv_proj(
    const float* __restrict__ qin, const float* __restrict__ kin,
    const float* __restrict__ vin, const int* __restrict__ mask,
    const unsigned short* __restrict__ wT,
    const float* __restrict__ bq, const float* __restrict__ bk,
    const float* __restrict__ bv,
    unsigned short* __restrict__ q_ws, unsigned short* __restrict__ kh_ws,
    unsigned short* __restrict__ vt_ws, float qscale)
{
  __shared__ unsigned short As[2][64 * 40];
  __shared__ unsigned short Ws[2][64 * 40];

  const int z = blockIdx.z;
  const float* A = (z == 0) ? qin : (z == 1) ? kin : vin;
  const unsigned short* W = wT + z * 65536;
  const float* bias = (z == 0) ? bq : (z == 1) ? bk : bv;
  const float bscale = (z == 0) ? qscale : 1.f;

  const int tid = threadIdx.x;
  const int lane = tid & 63;
  const int wv = tid >> 6;
  const int l16 = lane & 15, q4 = lane >> 4;
  const int Mblk = blockIdx.x * 64, Nblk = blockIdx.y * 64;
  const int M0 = Mblk + (wv & 1) * 32;
  const int N0 = Nblk + (wv >> 1) * 32;

  const int srow = tid >> 2, scol = (tid & 3) * 8;
  const float* Aps = A + (size_t)(Mblk + srow) * 256 + scol;
  const unsigned short* Wps = W + (size_t)(Nblk + srow) * 256 + scol;
  unsigned short* adst = &As[0][srow * 40 + scol];
  unsigned short* wdst = &Ws[0][srow * 40 + scol];

  f32x4 areg0, areg1; s16x8 wreg;

#define LOADCH(K) do {                                                         \
    areg0 = *(const f32x4*)(Aps + (K) * 32);                                   \
    areg1 = *(const f32x4*)(Aps + (K) * 32 + 4);                               \
    wreg  = *(const s16x8*)(Wps + (K) * 32);                                   \
  } while (0)
#define WRITECH(B) do {                                                        \
    *(s16x8*)(adst + (B) * (64 * 40)) = cvt_bf16x8(areg0, areg1);              \
    *(s16x8*)(wdst + (B) * (64 * 40)) = wreg;                                  \
  } while (0)

  f32x4 acc[2][2] = {};

  LOADCH(0); WRITECH(0); LOADCH(1);
  for (int k = 0; k < 8; ++k) {
    __syncthreads();
    if (k + 1 < 8) WRITECH((k + 1) & 1);
    if (k + 2 < 8) LOADCH(k + 2);
    const unsigned short* AL = &As[k & 1][0];
    const unsigned short* WL = &Ws[k & 1][0];
    s16x8 af[2], wf[2];
#pragma unroll
    for (int i = 0; i < 2; ++i)
      af[i] = *(const s16x8*)(AL + ((wv & 1) * 32 + i * 16 + l16) * 40 + q4 * 8);
#pragma unroll
    for (int j = 0; j < 2; ++j)
      wf[j] = *(const s16x8*)(WL + ((wv >> 1) * 32 + j * 16 + l16) * 40 + q4 * 8);
#pragma unroll
    for (int i = 0; i < 2; ++i)
#pragma unroll
      for (int j = 0; j < 2; ++j)
        acc[i][j] = __builtin_amdgcn_mfma_f32_16x16x32_bf16(af[i], wf[j], acc[i][j], 0, 0, 0);
  }
#undef LOADCH
#undef WRITECH

#pragma unroll
  for (int j = 0; j < 2; ++j) {
    int n = N0 + j * 16 + l16;
    float bb = bias[n] * bscale;
#pragma unroll
    for (int i = 0; i < 2; ++i) {
      int m0 = M0 + i * 16 + q4 * 4;   // 4 consecutive tokens
      f32x4 c = acc[i][j];
      c[0] += bb; c[1] += bb; c[2] += bb; c[3] += bb;
      if (z == 0) {
#pragma unroll
        for (int r = 0; r < 4; ++r)
          q_ws[(size_t)(m0 + r) * 256 + n] = bf16_rne(c[r]);
      } else if (z == 1) {
        int bi = m0 >> 12, s = m0 & 4095;
        int h = n >> 5, d = n & 31;
        unsigned short* o = kh_ws + ((size_t)(bi * 8 + h) * 4096 + s) * 32 + d;
#pragma unroll
        for (int r = 0; r < 4; ++r) o[(size_t)r * 32] = bf16_rne(c[r]);
      } else {
        // zero masked tokens' V rows (token == flat index m0+r)
#pragma unroll
        for (int r = 0; r < 4; ++r) c[r] *= (float)mask[m0 + r];
        int bi = m0 >> 12, s = m0 & 4095;
        int h = n >> 5, d = n & 31;
        int T = s >> 6, sl = s & 63;
        unsigned lo = (unsigned)bf16_rne(c[0]) | ((unsigned)bf16_rne(c[1]) << 16);
        unsigned hi = (unsigned)bf16_rne(c[2]) | ((unsigned)bf16_rne(c[3]) << 16);
        unsigned* dst = (unsigned*)(vt_ws +
            ((size_t)((bi * 8 + h) * 64 + T) * 32 + d) * 64 + sl);
        dst[0] = lo; dst[1] = hi;
      }
    }
  }
}

// ---------------------------------------------------------------------------
// flash v12 (byte-identical to r12's 73.7us kernel): split-K x4, ring-2 LDS,
// linear K staging stride 40, V stride 72, +0x8000 rounding, bf16 O partials.
// ---------------------------------------------------------------------------
__global__ __launch_bounds__(256, 7) void flash_kernel(
    const unsigned short* __restrict__ q_ws, const unsigned short* __restrict__ kh_ws,
    const unsigned short* __restrict__ vt_ws, const unsigned short* __restrict__ mbf,
    unsigned short* __restrict__ pO, float* __restrict__ pL)
{
  __shared__ unsigned short Kb[2][64 * 40];   // 10240 B
  __shared__ unsigned short Vb[2][32 * 72];   //  9216 B

  const int idx = blockIdx.x;            // 2048 blocks
  const int qt = idx & 31;
  const int kq = (idx >> 5) & 3;
  const int bh = idx >> 7;
  const int b = bh >> 3, h = bh & 7;
  const int tid = threadIdx.x;
  const int lane = tid & 63;
  const int wv = tid >> 6;
  const int l16 = lane & 15, q4 = lane >> 4;
  const int q0 = qt * 128 + wv * 32;

  s16x8 Qf[2];
#pragma unroll
  for (int qh = 0; qh < 2; ++qh)
    Qf[qh] = *(const s16x8*)(q_ws +
        (size_t)(b * 4096 + q0 + qh * 16 + l16) * 256 + h * 32 + q4 * 8);

  const unsigned short* Ksrc = kh_ws + ((size_t)bh * 4096 + kq * 1024) * 32;
  const unsigned short* Vsrc = vt_ws + (size_t)bh * 64 * 2048 + (size_t)kq * 16 * 2048;
  const unsigned short* Msrc = mbf + b * 4096 + kq * 1024 + q4 * 4;

  unsigned short* kdst = &Kb[0][(tid >> 2) * 40 + (tid & 3) * 8];
  unsigned short* vdst = &Vb[0][(tid >> 3) * 72 + (tid & 7) * 8];

  f32x4 o[2][2] = {{{0.f,0.f,0.f,0.f},{0.f,0.f,0.f,0.f}},
                   {{0.f,0.f,0.f,0.f},{0.f,0.f,0.f,0.f}}};
  f32x4 l[2] = {{0.f,0.f,0.f,0.f},{0.f,0.f,0.f,0.f}};

  const unsigned sel = (l16 == 0) ? 0xFFFFFFFFu : 0u;  // l-operand column select

  s16x8 kreg, vreg;

#define STAGE_LOAD(T) do {                                                     \
    kreg = *(const s16x8*)(Ksrc + (size_t)(T) * 2048 + tid * 8);               \
    vreg = *(const s16x8*)(Vsrc + (size_t)(T) * 2048 + tid * 8);               \
  } while (0)
#define STAGE_WRITE(B) do {                                                    \
    *(s16x8*)(kdst + (B) * (64 * 40)) = kreg;                                  \
    *(s16x8*)(vdst + (B) * (32 * 72)) = vreg;                                  \
  } while (0)

#define COMPUTE(B, T) do {                                                     \
    const unsigned short* KL = &Kb[B][0];                                      \
    const unsigned short* VL = &Vb[B][0];                                      \
    const f32x4 zz = {0.f, 0.f, 0.f, 0.f};                                     \
    s16x4 mreg[4];                                                             \
    _Pragma("unroll") for (int t = 0; t < 4; ++t)                              \
      mreg[t] = *(const s16x4*)(Msrc + (T) * 64 + t * 16);                     \
    _Pragma("unroll") for (int t = 0; t < 4; ++t) {                            \
      s16x8 kf = *(const s16x8*)(KL + (t * 16 + l16) * 40 + q4 * 8);           \
      f32x4 sc0 = __builtin_amdgcn_mfma_f32_16x16x32_bf16(kf, Qf[0], zz, 0, 0, 0); \
      f32x4 sc1 = __builtin_amdgcn_mfma_f32_16x16x32_bf16(kf, Qf[1], zz, 0, 0, 0); \
      unsigned a0 = __float_as_uint(__builtin_amdgcn_exp2f(sc0[0])) + 0x8000u; \
      unsigned a1 = __float_as_uint(__builtin_amdgcn_exp2f(sc0[1])) + 0x8000u; \
      unsigned a2 = __float_as_uint(__builtin_amdgcn_exp2f(sc0[2])) + 0x8000u; \
      unsigned a3 = __float_as_uint(__builtin_amdgcn_exp2f(sc0[3])) + 0x8000u; \
      unsigned c0 = __float_as_uint(__builtin_amdgcn_exp2f(sc1[0])) + 0x8000u; \
      unsigned c1 = __float_as_uint(__builtin_amdgcn_exp2f(sc1[1])) + 0x8000u; \
      unsigned c2 = __float_as_uint(__builtin_amdgcn_exp2f(sc1[2])) + 0x8000u; \
      unsigned c3 = __float_as_uint(__builtin_amdgcn_exp2f(sc1[3])) + 0x8000u; \
      u32x2 pk0, pk1;                                                          \
      pk0[0] = __builtin_amdgcn_perm(a1, a0, 0x07060302u);                     \
      pk0[1] = __builtin_amdgcn_perm(a3, a2, 0x07060302u);                     \
      pk1[0] = __builtin_amdgcn_perm(c1, c0, 0x07060302u);                     \
      pk1[1] = __builtin_amdgcn_perm(c3, c2, 0x07060302u);                     \
      s16x4 pf0 = __builtin_bit_cast(s16x4, pk0);                              \
      s16x4 pf1 = __builtin_bit_cast(s16x4, pk1);                              \
      u32x2 mm = __builtin_bit_cast(u32x2, mreg[t]);                           \
      mm[0] &= sel; mm[1] &= sel;                                              \
      s16x4 onesb = __builtin_bit_cast(s16x4, mm);                             \
      s16x4 vf0 = *(const s16x4*)(VL + l16 * 72 + t * 16 + q4 * 4);            \
      s16x4 vf1 = *(const s16x4*)(VL + (l16 + 16) * 72 + t * 16 + q4 * 4);     \
      o[0][0] = __builtin_amdgcn_mfma_f32_16x16x16bf16_1k(pf0, vf0, o[0][0], 0, 0, 0); \
      o[0][1] = __builtin_amdgcn_mfma_f32_16x16x16bf16_1k(pf0, vf1, o[0][1], 0, 0, 0); \
      o[1][0] = __builtin_amdgcn_mfma_f32_16x16x16bf16_1k(pf1, vf0, o[1][0], 0, 0, 0); \
      o[1][1] = __builtin_amdgcn_mfma_f32_16x16x16bf16_1k(pf1, vf1, o[1][1], 0, 0, 0); \
      l[0] = __builtin_amdgcn_mfma_f32_16x16x16bf16_1k(pf0, onesb, l[0], 0, 0, 0); \
      l[1] = __builtin_amdgcn_mfma_f32_16x16x16bf16_1k(pf1, onesb, l[1], 0, 0, 0); \
    }                                                                          \
  } while (0)

  STAGE_LOAD(0); STAGE_WRITE(0);
  STAGE_LOAD(1);

  for (int T = 0; T < 16; ++T) {
    __syncthreads();                       // fences buf[(T+1)&1] reuse
    if (T + 1 < 16) STAGE_WRITE((T + 1) & 1);   // from loads issued iter T-1
    if (T + 2 < 16) STAGE_LOAD(T + 2);          // in flight across COMPUTE
    COMPUTE(T & 1, T);
  }
#undef STAGE_LOAD
#undef STAGE_WRITE
#undef COMPUTE

  // bf16 partials: pO[kq][bh][q][d]; l (f32): pL[kq][bh][q]
  unsigned short* pob = pO + (((size_t)kq * 16 + bh) * 4096 + q0) * 32;
#pragma unroll
  for (int qh = 0; qh < 2; ++qh)
#pragma unroll
    for (int r = 0; r < 4; ++r) {
      int q = qh * 16 + q4 * 4 + r;
      pob[(size_t)q * 32 + l16]      = bf16_rne(o[qh][0][r]);
      pob[(size_t)q * 32 + l16 + 16] = bf16_rne(o[qh][1][r]);
    }
  if (l16 == 0) {
    float* plb = pL + ((size_t)kq * 16 + bh) * 4096 + q0;
#pragma unroll
    for (int qh = 0; qh < 2; ++qh)
#pragma unroll
      for (int r = 0; r < 4; ++r)
        plb[qh * 16 + q4 * 4 + r] = l[qh][r];
  }
}

// ---------------------------------------------------------------------------
// o_proj v2: LDS-staged GEMM with FUSED combine. A-tile for k-step k (head k,
// 32-wide k-slice) is built during staging: read 4 bf16 pO slabs + 4 f32 pL,
// normalize (sum O)/(sum l), round to bf16 -> LDS. Removes the combine kernel
// and the wtd round-trip; kills o_proj's 16-segment A gathers (the r5 disease).
// ---------------------------------------------------------------------------
__global__ __launch_bounds__(256) void o_proj(
    const unsigned short* __restrict__ pO, const float* __restrict__ pL,
    const unsigned short* __restrict__ woT,
    const float* __restrict__ bo, float* __restrict__ out)
{
  __shared__ unsigned short As[2][64 * 40];
  __shared__ unsigned short Ws[2][64 * 40];

  const int tid = threadIdx.x;
  const int lane = tid & 63;
  const int wv = tid >> 6;
  const int l16 = lane & 15, q4 = lane >> 4;
  const int Mblk = blockIdx.x * 64, Nblk = blockIdx.y * 64;
  const int M0 = Mblk + (wv & 1) * 32;
  const int N0 = Nblk + (wv >> 1) * 32;

  const int srow = tid >> 2, scol = (tid & 3) * 8;
  const int token = Mblk + srow;
  const int b = token >> 12, s = token & 4095;
  const unsigned short* Wps = woT + (size_t)(Nblk + srow) * 256 + scol;
  unsigned short* adst = &As[0][srow * 40 + scol];
  unsigned short* wdst = &Ws[0][srow * 40 + scol];

  const size_t OS = (size_t)16 * 4096 * 32;   // pO elements per kq slab
  const size_t LS = (size_t)16 * 4096;        // pL elements per kq slab

  s16x8 preg[4]; float lsum; s16x8 wreg;

#define LOADCH(K) do {                                                         \
    int _bh = b * 8 + (K);                                                     \
    size_t _i0 = ((size_t)_bh * 4096 + s) * 32 + scol;                         \
    preg[0] = *(const s16x8*)(pO + _i0);                                       \
    preg[1] = *(const s16x8*)(pO + OS + _i0);                                  \
    preg[2] = *(const s16x8*)(pO + 2 * OS + _i0);                              \
    preg[3] = *(const s16x8*)(pO + 3 * OS + _i0);                              \
    size_t _li = (size_t)_bh * 4096 + s;                                       \
    lsum = pL[_li] + pL[LS + _li] + pL[2 * LS + _li] + pL[3 * LS + _li];       \
    wreg = *(const s16x8*)(Wps + (K) * 32);                                    \
  } while (0)
#define WRITECH(B) do {                                                        \
    float inv = 1.0f / lsum;                                                   \
    s16x8 ap;                                                                  \
    _Pragma("unroll") for (int j = 0; j < 8; ++j) {                            \
      float v = bf16_to_f32((unsigned short)preg[0][j])                        \
              + bf16_to_f32((unsigned short)preg[1][j])                        \
              + bf16_to_f32((unsigned short)preg[2][j])                        \
              + bf16_to_f32((unsigned short)preg[3][j]);                       \
      ap[j] = (short)bf16_rne(v * inv);                                        \
    }                                                                          \
    *(s16x8*)(adst + (B) * (64 * 40)) = ap;                                    \
    *(s16x8*)(wdst + (B) * (64 * 40)) = wreg;                                  \
  } while (0)

  f32x4 acc[2][2] = {};

  LOADCH(0); WRITECH(0); LOADCH(1);
  for (int k = 0; k < 8; ++k) {
    __syncthreads();
    if (k + 1 < 8) WRITECH((k + 1) & 1);
    if (k + 2 < 8) LOADCH(k + 2);
    const unsigned short* AL = &As[k & 1][0];
    const unsigned short* WL = &Ws[k & 1][0];
    s16x8 af[2], wf[2];
#pragma unroll
    for (int i = 0; i < 2; ++i)
      af[i] = *(const s16x8*)(AL + ((wv & 1) * 32 + i * 16 + l16) * 40 + q4 * 8);
#pragma unroll
    for (int j = 0; j < 2; ++j)
      wf[j] = *(const s16x8*)(WL + ((wv >> 1) * 32 + j * 16 + l16) * 40 + q4 * 8);
#pragma unroll
    for (int i = 0; i < 2; ++i)
#pragma unroll
      for (int j = 0; j < 2; ++j)
        acc[i][j] = __builtin_amdgcn_mfma_f32_16x16x32_bf16(af[i], wf[j], acc[i][j], 0, 0, 0);
  }
#undef LOADCH
#undef WRITECH

#pragma unroll
  for (int j = 0; j < 2; ++j) {
    int n = N0 + j * 16 + l16;
    float bb = bo[n];
#pragma unroll
    for (int i = 0; i < 2; ++i) {
      int m0 = M0 + i * 16 + q4 * 4;
#pragma unroll
      for (int r = 0; r < 4; ++r)
        out[(size_t)(m0 + r) * 256 + n] = acc[i][j][r] + bb;
    }
  }
}

// ---------------------------------------------------------------------------
extern "C" void kernel_launch(void* const* d_in, const int* in_sizes, int n_in,
                              void* d_out, int out_size, void* d_ws, size_t ws_size,
                              hipStream_t stream) {
  const float* query = (const float*)d_in[0];
  const float* key   = (const float*)d_in[1];
  const float* value = (const float*)d_in[2];
  const int*   mask  = (const int*)d_in[3];
  const float* Wq = (const float*)d_in[4];
  const float* bq = (const float*)d_in[5];
  const float* Wk = (const float*)d_in[6];
  const float* bk = (const float*)d_in[7];
  const float* Wv = (const float*)d_in[8];
  const float* bv = (const float*)d_in[9];
  const float* Wo = (const float*)d_in[10];
  const float* bo = (const float*)d_in[11];
  float* out = (float*)d_out;

  char* p = (char*)d_ws;
  unsigned short* q_ws  = (unsigned short*)p; p += (size_t)NTOK * HID * 2;
  unsigned short* kh_ws = (unsigned short*)p; p += (size_t)NTOK * HID * 2;
  unsigned short* vt_ws = (unsigned short*)p; p += (size_t)NTOK * HID * 2;
  unsigned short* wT    = (unsigned short*)p; p += (size_t)4 * 65536 * 2;
  unsigned short* mbf   = (unsigned short*)p; p += (size_t)NTOK * 2;
  unsigned short* pO    = (unsigned short*)p; p += (size_t)4 * 16 * 4096 * 32 * 2;
  float* pL             = (float*)p;          p += (size_t)4 * 16 * 4096 * 4;

  const float qscale = 1.0f / (sqrtf(32.0f) * logf(2.0f)); // softmax scale + log2 domain

  prep_kernel<<<(4 * 65536 + NTOK + 255) / 256, 256, 0, stream>>>(
      Wq, Wk, Wv, Wo, mask, wT, mbf, qscale);
  qkv_proj<<<dim3(NTOK / 64, HID / 64, 3), 256, 0, stream>>>(
      query, key, value, mask, wT, bq, bk, bv, q_ws, kh_ws, vt_ws, qscale);
  flash_kernel<<<dim3(2048), 256, 0, stream>>>(
      q_ws, kh_ws, vt_ws, mbf, pO, pL);
  o_proj<<<dim3(NTOK / 64, HID / 64), 256, 0, stream>>>(
      pO, pL, wT + 3 * 65536, bo, out);
}